// Round 1
// baseline (1097.270 us; speedup 1.0000x reference)
//
#include <hip/hip_runtime.h>
#include <hip/hip_bf16.h>

#define DEV static __device__ __forceinline__

DEV int reflect_idx(int q, int L) {
    q = q < 0 ? -q : q;
    q = q >= L ? 2 * L - 2 - q : q;
    return q;
}

DEV unsigned short f2bf(float f) {
    unsigned int b = __float_as_uint(f);
    unsigned int r = (b + 0x7FFFu + ((b >> 16) & 1u)) >> 16;
    return (unsigned short)r;
}
DEV float bf2f(unsigned short u) {
    return __uint_as_float(((unsigned int)u) << 16);
}

// ---------------------------------------------------------------------------
// prep: zero loss accumulators
__global__ void k0_init(float* lacc) {
    if (threadIdx.x < 8) lacc[threadIdx.x] = 0.0f;
}

// prep: transpose w1 [256][512][3] -> w1t [512][3][256]
__global__ void kt_w1(const float* __restrict__ w1, float* __restrict__ w1t) {
    int idx = blockIdx.x * 256 + threadIdx.x;        // 393216
    int co = idx & 255;
    int rk = idx >> 8;                                // ci*3+k in [0,1536)
    w1t[idx] = w1[co * 1536 + rk];
}

// prep: transpose w2 [32][256][3] -> w2t [256][3][32]
__global__ void kt_w2(const float* __restrict__ w2, float* __restrict__ w2t) {
    int idx = blockIdx.x * 256 + threadIdx.x;        // 24576
    int co = idx & 31;
    int rk = idx >> 5;                                // ci*3+k in [0,768)
    w2t[idx] = w2[co * 768 + rk];
}

// ---------------------------------------------------------------------------
// K1: conv1 (512->256, d=8, reflect pad 8, L=1024) + bn1 + relu -> y1 (bf16)
// grid (16 t-tiles, 64 n), block 256. Per block: all 256 co x 64 t.
// Thread: tt=tid&7 (t=t0+tt*8..+7), cc=tid>>3 (co=cc*8..+7). acc[8co][8t].
__global__ __launch_bounds__(256, 3) void k1_conv1(
    const float* __restrict__ x, const float* __restrict__ w1t,
    const float* __restrict__ g, const float* __restrict__ be,
    const float* __restrict__ mn, const float* __restrict__ vr,
    unsigned short* __restrict__ y1)
{
    const int tid = threadIdx.x;
    const int tt = tid & 7;
    const int cc = tid >> 3;
    const int t0 = blockIdx.x * 64;
    const int n  = blockIdx.y;

    __shared__ float xs[8][80];       // 8 ci x (64 + 2*8) cols
    __shared__ float wsh[8 * 3 * 256];

    float acc[8][8];
#pragma unroll
    for (int c = 0; c < 8; ++c)
#pragma unroll
        for (int t = 0; t < 8; ++t) acc[c][t] = 0.0f;

    const float* xn = x + (size_t)n * 512 * 1024;

    for (int c0 = 0; c0 < 512; c0 += 8) {
        __syncthreads();
        // stage x chunk: 8 rows x 80 cols
        for (int idx = tid; idx < 640; idx += 256) {
            int r = idx / 80;
            int col = idx - r * 80;
            int q = reflect_idx(t0 - 8 + col, 1024);
            xs[r][col] = xn[(c0 + r) * 1024 + q];
        }
        // stage w chunk: [ci][k][co] 8*3*256
        for (int idx = tid; idx < 6144; idx += 256) {
            wsh[idx] = w1t[c0 * 768 + idx];
        }
        __syncthreads();
#pragma unroll
        for (int i = 0; i < 8; ++i) {
            float xv[24];
#pragma unroll
            for (int jj = 0; jj < 6; ++jj)
                *(float4*)&xv[jj * 4] = *(const float4*)&xs[i][tt * 8 + jj * 4];
#pragma unroll
            for (int k = 0; k < 3; ++k) {
                float wv[8];
                *(float4*)&wv[0] = *(const float4*)&wsh[(i * 3 + k) * 256 + cc * 8];
                *(float4*)&wv[4] = *(const float4*)&wsh[(i * 3 + k) * 256 + cc * 8 + 4];
#pragma unroll
                for (int c = 0; c < 8; ++c)
#pragma unroll
                    for (int t = 0; t < 8; ++t)
                        acc[c][t] = fmaf(wv[c], xv[k * 8 + t], acc[c][t]);
            }
        }
    }

    // epilogue: bn + relu, store bf16
#pragma unroll
    for (int c = 0; c < 8; ++c) {
        int co = cc * 8 + c;
        float inv = g[co] / sqrtf(vr[co] + 1e-5f);
        float sh  = be[co] - mn[co] * inv;
        unsigned short pk[8];
#pragma unroll
        for (int t = 0; t < 8; ++t) {
            float r = fmaxf(fmaf(acc[c][t], inv, sh), 0.0f);
            pk[t] = f2bf(r);
        }
        size_t base = ((size_t)n * 256 + co) * 1024 + t0 + tt * 8;
        *(uint4*)&y1[base] = *(const uint4*)&pk[0];
    }
}

// ---------------------------------------------------------------------------
// K2: upsample2(y1) -> conv2 (256->32, d=16, reflect pad 16, L=2048) + bn2 + relu
// grid (8 t-tiles, 64 n), block 256. Per block: 32 co x 256 t.
// Thread: tt=tid&31 (t=t0+tt*8..+7), cc=tid>>5 (co=cc*4..+3). acc[4co][8t].
__global__ __launch_bounds__(256, 4) void k2_conv2(
    const unsigned short* __restrict__ y1, const float* __restrict__ w2t,
    const float* __restrict__ g, const float* __restrict__ be,
    const float* __restrict__ mn, const float* __restrict__ vr,
    float* __restrict__ y2)
{
    const int tid = threadIdx.x;
    const int tt = tid & 31;
    const int cc = tid >> 5;
    const int t0 = blockIdx.x * 256;
    const int n  = blockIdx.y;

    __shared__ float us[8][288];      // 8 ci x (256 + 2*16) cols
    __shared__ float wsh[8 * 3 * 32];

    float acc[4][8];
#pragma unroll
    for (int c = 0; c < 4; ++c)
#pragma unroll
        for (int t = 0; t < 8; ++t) acc[c][t] = 0.0f;

    for (int c0 = 0; c0 < 256; c0 += 8) {
        __syncthreads();
        // stage upsampled input chunk
        for (int idx = tid; idx < 8 * 288; idx += 256) {
            int r = idx / 288;
            int col = idx - r * 288;
            int q = reflect_idx(t0 - 16 + col, 2048);
            float src = fmaxf((float)q * 0.5f - 0.25f, 0.0f);
            int i0 = (int)src;
            float w = src - (float)i0;
            int i1 = i0 + 1 > 1023 ? 1023 : i0 + 1;
            const unsigned short* row = y1 + ((size_t)n * 256 + c0 + r) * 1024;
            float a = bf2f(row[i0]);
            float b = bf2f(row[i1]);
            us[r][col] = a + w * (b - a);
        }
        for (int idx = tid; idx < 768; idx += 256)
            wsh[idx] = w2t[c0 * 96 + idx];
        __syncthreads();
#pragma unroll
        for (int i = 0; i < 8; ++i) {
            float xv[24];
            *(float4*)&xv[0]  = *(const float4*)&us[i][tt * 8 + 0];
            *(float4*)&xv[4]  = *(const float4*)&us[i][tt * 8 + 4];
            *(float4*)&xv[8]  = *(const float4*)&us[i][tt * 8 + 16];
            *(float4*)&xv[12] = *(const float4*)&us[i][tt * 8 + 20];
            *(float4*)&xv[16] = *(const float4*)&us[i][tt * 8 + 32];
            *(float4*)&xv[20] = *(const float4*)&us[i][tt * 8 + 36];
#pragma unroll
            for (int k = 0; k < 3; ++k) {
                float4 wv = *(const float4*)&wsh[(i * 3 + k) * 32 + cc * 4];
#pragma unroll
                for (int t = 0; t < 8; ++t) {
                    acc[0][t] = fmaf(wv.x, xv[k * 8 + t], acc[0][t]);
                    acc[1][t] = fmaf(wv.y, xv[k * 8 + t], acc[1][t]);
                    acc[2][t] = fmaf(wv.z, xv[k * 8 + t], acc[2][t]);
                    acc[3][t] = fmaf(wv.w, xv[k * 8 + t], acc[3][t]);
                }
            }
        }
    }

#pragma unroll
    for (int c = 0; c < 4; ++c) {
        int co = cc * 4 + c;
        float inv = g[co] / sqrtf(vr[co] + 1e-5f);
        float sh  = be[co] - mn[co] * inv;
        float4 o0, o1;
        o0.x = fmaxf(fmaf(acc[c][0], inv, sh), 0.0f);
        o0.y = fmaxf(fmaf(acc[c][1], inv, sh), 0.0f);
        o0.z = fmaxf(fmaf(acc[c][2], inv, sh), 0.0f);
        o0.w = fmaxf(fmaf(acc[c][3], inv, sh), 0.0f);
        o1.x = fmaxf(fmaf(acc[c][4], inv, sh), 0.0f);
        o1.y = fmaxf(fmaf(acc[c][5], inv, sh), 0.0f);
        o1.z = fmaxf(fmaf(acc[c][6], inv, sh), 0.0f);
        o1.w = fmaxf(fmaf(acc[c][7], inv, sh), 0.0f);
        size_t base = ((size_t)n * 32 + co) * 2048 + t0 + tt * 8;
        *(float4*)&y2[base] = o0;
        *(float4*)&y2[base + 4] = o1;
    }
}

// ---------------------------------------------------------------------------
// K3: upsample2(y2) -> conv3 (32->3, d=32, reflect pad 32, L=4096) + bias,
// write transposed output out[((b*3+c)*4096 + t)*4 + s], n = b*4+s.
// grid (16 t-tiles, 64 n), block 256: one t per thread.
__global__ __launch_bounds__(256, 4) void k3_out(
    const float* __restrict__ y2, const float* __restrict__ w3,
    const float* __restrict__ bias, float* __restrict__ out)
{
    const int tid = threadIdx.x;
    const int t0 = blockIdx.x * 256;
    const int n  = blockIdx.y;

    __shared__ float us[32][320];     // 32 ci x (256 + 2*32) cols
    __shared__ float wsh[288];        // w_out [3][32][3] verbatim

    for (int idx = tid; idx < 288; idx += 256) wsh[idx] = w3[idx];

    const float* yn = y2 + (size_t)n * 32 * 2048;
    for (int idx = tid; idx < 32 * 320; idx += 256) {
        int r = idx / 320;
        int col = idx - r * 320;
        int q = reflect_idx(t0 - 32 + col, 4096);
        float src = fmaxf((float)q * 0.5f - 0.25f, 0.0f);
        int i0 = (int)src;
        float w = src - (float)i0;
        int i1 = i0 + 1 > 2047 ? 2047 : i0 + 1;
        const float* row = yn + r * 2048;
        float a = row[i0];
        float b = row[i1];
        us[r][col] = a + w * (b - a);
    }
    __syncthreads();

    float a0 = 0.0f, a1 = 0.0f, a2 = 0.0f;
#pragma unroll 8
    for (int ci = 0; ci < 32; ++ci) {
        float x0 = us[ci][tid];
        float x1 = us[ci][tid + 32];
        float x2 = us[ci][tid + 64];
        a0 = fmaf(wsh[(0 * 32 + ci) * 3 + 0], x0, a0);
        a0 = fmaf(wsh[(0 * 32 + ci) * 3 + 1], x1, a0);
        a0 = fmaf(wsh[(0 * 32 + ci) * 3 + 2], x2, a0);
        a1 = fmaf(wsh[(1 * 32 + ci) * 3 + 0], x0, a1);
        a1 = fmaf(wsh[(1 * 32 + ci) * 3 + 1], x1, a1);
        a1 = fmaf(wsh[(1 * 32 + ci) * 3 + 2], x2, a1);
        a2 = fmaf(wsh[(2 * 32 + ci) * 3 + 0], x0, a2);
        a2 = fmaf(wsh[(2 * 32 + ci) * 3 + 1], x1, a2);
        a2 = fmaf(wsh[(2 * 32 + ci) * 3 + 2], x2, a2);
    }
    int b = n >> 2, s = n & 3;
    int t = t0 + tid;
    size_t ob = ((size_t)(b * 3) * 4096 + t) * 4 + s;
    out[ob]         = a0 + bias[0];
    out[ob + 16384] = a1 + bias[1];
    out[ob + 32768] = a2 + bias[2];
}

// ---------------------------------------------------------------------------
// K4a: valid[b,s] = any(targets[b,:,:,s] != 0); count into lacc[1] (int)
__global__ void k4a_valid(const float* __restrict__ tg, float* lacc) {
    __shared__ int flag;
    if (threadIdx.x == 0) flag = 0;
    __syncthreads();
    int b = blockIdx.x >> 2, s = blockIdx.x & 3;
    bool any = false;
    for (int idx = threadIdx.x; idx < 3 * 4096; idx += 256) {
        int c = idx >> 12, t = idx & 4095;
        float v = tg[((size_t)(b * 3 + c) * 4096 + t) * 4 + s];
        any |= (v != 0.0f);
    }
    if (any) flag = 1;
    __syncthreads();
    if (threadIdx.x == 0 && flag) atomicAdd((int*)(lacc + 1), 1);
}

// K4b: sum over all (b,t,s) of sum_c targets*(lse - x_c); atomic per block
__global__ __launch_bounds__(256) void k4b_ce(
    const float* __restrict__ x, const float* __restrict__ tg, float* lacc)
{
    int i = blockIdx.x * 256 + threadIdx.x;   // 262144 (b,t,s) items
    int s = i & 3;
    int t = (i >> 2) & 4095;
    int b = i >> 14;
    size_t base = ((size_t)(b * 3) * 4096 + t) * 4 + s;
    float x0 = x[base], x1 = x[base + 16384], x2 = x[base + 32768];
    float mx = fmaxf(x0, fmaxf(x1, x2));
    float e0 = expf(x0 - mx), e1 = expf(x1 - mx), e2 = expf(x2 - mx);
    float lse = mx + logf(e0 + e1 + e2);
    float g0 = tg[base], g1 = tg[base + 16384], g2 = tg[base + 32768];
    float v = g0 * (lse - x0) + g1 * (lse - x1) + g2 * (lse - x2);

    for (int off = 32; off > 0; off >>= 1) v += __shfl_down(v, off);
    __shared__ float wsum[4];
    int lane = threadIdx.x & 63, wid = threadIdx.x >> 6;
    if (lane == 0) wsum[wid] = v;
    __syncthreads();
    if (threadIdx.x == 0) {
        atomicAdd(lacc, wsum[0] + wsum[1] + wsum[2] + wsum[3]);
    }
}

// K4c: loss = sum / (num * T)
__global__ void k4c_final(const float* lacc, float* out) {
    if (threadIdx.x == 0) {
        float sum = lacc[0];
        int num = ((const int*)lacc)[1];
        out[786432] = sum / ((float)num * 4096.0f);
    }
}

// ---------------------------------------------------------------------------
extern "C" void kernel_launch(void* const* d_in, const int* in_sizes, int n_in,
                              void* d_out, int out_size, void* d_ws, size_t ws_size,
                              hipStream_t stream) {
    (void)in_sizes; (void)n_in; (void)out_size; (void)ws_size;
    const float* fusion  = (const float*)d_in[0];
    const float* targets = (const float*)d_in[1];
    const float* w1  = (const float*)d_in[2];
    const float* g1  = (const float*)d_in[3];
    const float* be1 = (const float*)d_in[4];
    const float* mn1 = (const float*)d_in[5];
    const float* vr1 = (const float*)d_in[6];
    const float* w2  = (const float*)d_in[7];
    const float* g2  = (const float*)d_in[8];
    const float* be2 = (const float*)d_in[9];
    const float* mn2 = (const float*)d_in[10];
    const float* vr2 = (const float*)d_in[11];
    const float* w3  = (const float*)d_in[12];
    const float* b3  = (const float*)d_in[13];
    float* out = (float*)d_out;

    char* ws = (char*)d_ws;
    unsigned short* y1 = (unsigned short*)ws;              // 33,554,432 B
    float* y2   = (float*)(ws + 33554432);                 // 16,777,216 B
    float* w1t  = (float*)(ws + 50331648);                 //  1,572,864 B
    float* w2t  = (float*)(ws + 51904512);                 //     98,304 B
    float* lacc = (float*)(ws + 52002816);                 //        256 B

    k0_init<<<1, 64, 0, stream>>>(lacc);
    kt_w1<<<1536, 256, 0, stream>>>(w1, w1t);
    kt_w2<<<96, 256, 0, stream>>>(w2, w2t);
    k1_conv1<<<dim3(16, 64), 256, 0, stream>>>(fusion, w1t, g1, be1, mn1, vr1, y1);
    k2_conv2<<<dim3(8, 64), 256, 0, stream>>>(y1, w2t, g2, be2, mn2, vr2, y2);
    k3_out<<<dim3(16, 64), 256, 0, stream>>>(y2, w3, b3, out);
    k4a_valid<<<64, 256, 0, stream>>>(targets, lacc);
    k4b_ce<<<1024, 256, 0, stream>>>(out, targets, lacc);
    k4c_final<<<1, 64, 0, stream>>>(lacc, out);
}

// Round 2
// 596.973 us; speedup vs baseline: 1.8381x; 1.8381x over previous
//
#include <hip/hip_runtime.h>
#include <hip/hip_bf16.h>

#define DEV static __device__ __forceinline__

typedef short bf16x8_t __attribute__((ext_vector_type(8)));
typedef float f32x4 __attribute__((ext_vector_type(4)));

#define GLDS16(gp, lp) __builtin_amdgcn_global_load_lds( \
    (const __attribute__((address_space(1))) void*)(gp), \
    (__attribute__((address_space(3))) void*)(lp), 16, 0, 0)

DEV int reflect_idx(int q, int L) {
    q = q < 0 ? -q : q;
    q = q >= L ? 2 * L - 2 - q : q;
    return q;
}

DEV unsigned short f2bf(float f) {
    unsigned int b = __float_as_uint(f);
    unsigned int r = (b + 0x7FFFu + ((b >> 16) & 1u)) >> 16;
    return (unsigned short)r;
}
DEV float bf2f(unsigned short u) {
    return __uint_as_float(((unsigned int)u) << 16);
}

// ---------------------------------------------------------------------------
__global__ void k0_init(float* lacc) {
    if (threadIdx.x < 8) lacc[threadIdx.x] = 0.0f;
}

// prep: w1 [256co][512ci][3kk] fp32 -> wb [3kk][256co][512ci] bf16
__global__ void kw1b(const float* __restrict__ w1, unsigned short* __restrict__ wb) {
    int idx = blockIdx.x * 256 + threadIdx.x;   // 393216
    int kk = idx >> 17;
    int rem = idx & 131071;
    int co = rem >> 9;
    int ci = rem & 511;
    wb[idx] = f2bf(w1[(co * 512 + ci) * 3 + kk]);
}

// prep: transpose w2 [32][256][3] -> w2t [256][3][32] (fp32, for k2)
__global__ void kt_w2(const float* __restrict__ w2, float* __restrict__ w2t) {
    int idx = blockIdx.x * 256 + threadIdx.x;   // 24576
    int co = idx & 31;
    int rk = idx >> 5;
    w2t[idx] = w2[co * 768 + rk];
}

// prep: transpose x[n][512ci][1024t] fp32 -> xb[nr][1024t][512ci] bf16 (16 n per round)
__global__ __launch_bounds__(256) void kx_t(const float* __restrict__ x,
                                            unsigned short* __restrict__ xb, int n0) {
    __shared__ float ls[64][65];
    const int tid = threadIdx.x;
    const int t0 = blockIdx.x * 64, ci0 = blockIdx.y * 64;
    const int n = n0 + blockIdx.z;
    const float* xp = x + ((size_t)n * 512 + ci0) * 1024 + t0;
    for (int idx = tid; idx < 1024; idx += 256) {
        int r = idx >> 4, c4 = (idx & 15) * 4;
        float4 v = *(const float4*)(xp + r * 1024 + c4);
        ls[r][c4] = v.x; ls[r][c4 + 1] = v.y; ls[r][c4 + 2] = v.z; ls[r][c4 + 3] = v.w;
    }
    __syncthreads();
    unsigned short* xo = xb + ((size_t)blockIdx.z * 1024 + t0) * 512 + ci0;
#pragma unroll
    for (int p = 0; p < 2; ++p) {
        int trow = (tid >> 3) + p * 32;
        int cj = (tid & 7) * 8;
        unsigned short pk[8];
#pragma unroll
        for (int j = 0; j < 8; ++j) pk[j] = f2bf(ls[cj + j][trow]);
        *(uint4*)(xo + (size_t)trow * 512 + cj) = *(const uint4*)pk;
    }
}

// ---------------------------------------------------------------------------
// K1: conv1 (512->256, d=8, reflect) + bn1 + relu via bf16 MFMA 16x16x32.
// Block 256 thr = 4 waves; tile 256co x 64t; wave = 64co x 64t (4cs x 4ts).
// K-chunks of 32ci, double-buffered LDS (global_load_lds w=16, swizzled gather).
// D[m=t][n=co]: A = X (m=t, k=ci), B = W (n=co, k=ci).
__global__ __launch_bounds__(256, 1) void k1_mfma(
    const unsigned short* __restrict__ xb, const unsigned short* __restrict__ wb,
    const float* __restrict__ g, const float* __restrict__ be,
    const float* __restrict__ mn, const float* __restrict__ vr,
    unsigned short* __restrict__ y1, int n0)
{
    const int tid  = threadIdx.x;
    const int lane = tid & 63;
    const int w    = tid >> 6;
    const int tq   = lane & 15;
    const int qd   = lane >> 4;
    const int t0   = blockIdx.x * 64;
    const int nr   = blockIdx.y;
    const int n    = n0 + nr;

    __shared__ unsigned short xs[2][80 * 32];   // 80 rows x 64B per buffer

    // staging gather pointers (swizzle f(r) = (r>>1)&3 applied on global side)
    const int r1 = tid >> 2;
    const int q1 = (tid & 3) ^ ((r1 >> 1) & 3);
    const unsigned short* gp0 =
        xb + ((size_t)nr * 1024 + reflect_idx(t0 - 8 + r1, 1024)) * 512 + q1 * 8;
    const unsigned short* gp1 =
        xb + ((size_t)nr * 1024 + reflect_idx(t0 - 8 + 64 + r1, 1024)) * 512 + q1 * 8;

    // fragment-read lane constants: atom = qd ^ ((tq>>1)&3)
    const int atom = qd ^ ((tq >> 1) & 3);
    const int xoff = tq * 32 + atom * 8;        // ushort offset within buffer

    f32x4 acc[4][4];
#pragma unroll
    for (int a = 0; a < 4; ++a)
#pragma unroll
        for (int b = 0; b < 4; ++b) acc[a][b] = (f32x4){0.f, 0.f, 0.f, 0.f};

    // W lane base: wb[(kk*256 + w*64 + cs*16 + tq)*512 + qd*8 + c*32]
    const unsigned short* wlane = wb + ((size_t)(w * 64 + tq)) * 512 + qd * 8;

    // prologue: stage chunk 0, preload W chunk 0
    GLDS16(gp0, &xs[0][tid * 8]);
    if (tid < 64) GLDS16(gp1, &xs[0][(256 + tid) * 8]);

    bf16x8_t Wf[4][3];
#pragma unroll
    for (int cs = 0; cs < 4; ++cs)
#pragma unroll
        for (int kk = 0; kk < 3; ++kk)
            Wf[cs][kk] = *(const bf16x8_t*)(wlane + (size_t)(kk * 256 + cs * 16) * 512);
    __syncthreads();

#pragma unroll
    for (int c = 0; c < 16; ++c) {
        const int pb = c & 1;
        if (c < 15) {
            GLDS16(gp0 + (c + 1) * 32, &xs[pb ^ 1][tid * 8]);
            if (tid < 64) GLDS16(gp1 + (c + 1) * 32, &xs[pb ^ 1][(256 + tid) * 8]);
        }
        bf16x8_t Wn[4][3];
        if (c < 15) {
#pragma unroll
            for (int cs = 0; cs < 4; ++cs)
#pragma unroll
                for (int kk = 0; kk < 3; ++kk)
                    Wn[cs][kk] = *(const bf16x8_t*)(wlane + (size_t)(kk * 256 + cs * 16) * 512 + (c + 1) * 32);
        }
#pragma unroll
        for (int ts = 0; ts < 4; ++ts) {
            bf16x8_t Xf[3];
#pragma unroll
            for (int kk = 0; kk < 3; ++kk)
                Xf[kk] = *(const bf16x8_t*)&xs[pb][xoff + (ts * 16 + kk * 8) * 32];
#pragma unroll
            for (int cs = 0; cs < 4; ++cs)
#pragma unroll
                for (int kk = 0; kk < 3; ++kk)
                    acc[ts][cs] = __builtin_amdgcn_mfma_f32_16x16x32_bf16(
                        Xf[kk], Wf[cs][kk], acc[ts][cs], 0, 0, 0);
        }
        __syncthreads();
        if (c < 15) {
#pragma unroll
            for (int cs = 0; cs < 4; ++cs)
#pragma unroll
                for (int kk = 0; kk < 3; ++kk)
                    Wf[cs][kk] = Wn[cs][kk];
        }
    }

    // epilogue: bn + relu, bf16 pack, 8B stores (lane holds 4 consecutive t)
#pragma unroll
    for (int cs = 0; cs < 4; ++cs) {
        int co = w * 64 + cs * 16 + tq;
        float iv = g[co] / sqrtf(vr[co] + 1e-5f);
        float sh = be[co] - mn[co] * iv;
        unsigned short* yp = y1 + ((size_t)(n * 256 + co)) * 1024 + t0 + qd * 4;
#pragma unroll
        for (int ts = 0; ts < 4; ++ts) {
            unsigned short pk[4];
#pragma unroll
            for (int rg = 0; rg < 4; ++rg)
                pk[rg] = f2bf(fmaxf(fmaf(acc[ts][cs][rg], iv, sh), 0.0f));
            *(uint2*)(yp + ts * 16) = *(const uint2*)pk;
        }
    }
}

// ---------------------------------------------------------------------------
// K2: upsample2(y1) -> conv2 (256->32, d=16) + bn2 + relu  (fp32, unchanged)
__global__ __launch_bounds__(256, 4) void k2_conv2(
    const unsigned short* __restrict__ y1, const float* __restrict__ w2t,
    const float* __restrict__ g, const float* __restrict__ be,
    const float* __restrict__ mn, const float* __restrict__ vr,
    float* __restrict__ y2)
{
    const int tid = threadIdx.x;
    const int tt = tid & 31;
    const int cc = tid >> 5;
    const int t0 = blockIdx.x * 256;
    const int n  = blockIdx.y;

    __shared__ float us[8][288];
    __shared__ float wsh[8 * 3 * 32];

    float acc[4][8];
#pragma unroll
    for (int c = 0; c < 4; ++c)
#pragma unroll
        for (int t = 0; t < 8; ++t) acc[c][t] = 0.0f;

    for (int c0 = 0; c0 < 256; c0 += 8) {
        __syncthreads();
        for (int idx = tid; idx < 8 * 288; idx += 256) {
            int r = idx / 288;
            int col = idx - r * 288;
            int q = reflect_idx(t0 - 16 + col, 2048);
            float src = fmaxf((float)q * 0.5f - 0.25f, 0.0f);
            int i0 = (int)src;
            float w = src - (float)i0;
            int i1 = i0 + 1 > 1023 ? 1023 : i0 + 1;
            const unsigned short* row = y1 + ((size_t)n * 256 + c0 + r) * 1024;
            float a = bf2f(row[i0]);
            float b = bf2f(row[i1]);
            us[r][col] = a + w * (b - a);
        }
        for (int idx = tid; idx < 768; idx += 256)
            wsh[idx] = w2t[c0 * 96 + idx];
        __syncthreads();
#pragma unroll
        for (int i = 0; i < 8; ++i) {
            float xv[24];
            *(float4*)&xv[0]  = *(const float4*)&us[i][tt * 8 + 0];
            *(float4*)&xv[4]  = *(const float4*)&us[i][tt * 8 + 4];
            *(float4*)&xv[8]  = *(const float4*)&us[i][tt * 8 + 16];
            *(float4*)&xv[12] = *(const float4*)&us[i][tt * 8 + 20];
            *(float4*)&xv[16] = *(const float4*)&us[i][tt * 8 + 32];
            *(float4*)&xv[20] = *(const float4*)&us[i][tt * 8 + 36];
#pragma unroll
            for (int k = 0; k < 3; ++k) {
                float4 wv = *(const float4*)&wsh[(i * 3 + k) * 32 + cc * 4];
#pragma unroll
                for (int t = 0; t < 8; ++t) {
                    acc[0][t] = fmaf(wv.x, xv[k * 8 + t], acc[0][t]);
                    acc[1][t] = fmaf(wv.y, xv[k * 8 + t], acc[1][t]);
                    acc[2][t] = fmaf(wv.z, xv[k * 8 + t], acc[2][t]);
                    acc[3][t] = fmaf(wv.w, xv[k * 8 + t], acc[3][t]);
                }
            }
        }
    }

#pragma unroll
    for (int c = 0; c < 4; ++c) {
        int co = cc * 4 + c;
        float inv = g[co] / sqrtf(vr[co] + 1e-5f);
        float sh  = be[co] - mn[co] * inv;
        float4 o0, o1;
        o0.x = fmaxf(fmaf(acc[c][0], inv, sh), 0.0f);
        o0.y = fmaxf(fmaf(acc[c][1], inv, sh), 0.0f);
        o0.z = fmaxf(fmaf(acc[c][2], inv, sh), 0.0f);
        o0.w = fmaxf(fmaf(acc[c][3], inv, sh), 0.0f);
        o1.x = fmaxf(fmaf(acc[c][4], inv, sh), 0.0f);
        o1.y = fmaxf(fmaf(acc[c][5], inv, sh), 0.0f);
        o1.z = fmaxf(fmaf(acc[c][6], inv, sh), 0.0f);
        o1.w = fmaxf(fmaf(acc[c][7], inv, sh), 0.0f);
        size_t base = ((size_t)n * 32 + co) * 2048 + t0 + tt * 8;
        *(float4*)&y2[base] = o0;
        *(float4*)&y2[base + 4] = o1;
    }
}

// ---------------------------------------------------------------------------
// K3: upsample2(y2) -> conv3 (32->3, d=32) + bias, transposed store (unchanged)
__global__ __launch_bounds__(256, 4) void k3_out(
    const float* __restrict__ y2, const float* __restrict__ w3,
    const float* __restrict__ bias, float* __restrict__ out)
{
    const int tid = threadIdx.x;
    const int t0 = blockIdx.x * 256;
    const int n  = blockIdx.y;

    __shared__ float us[32][320];
    __shared__ float wsh[288];

    for (int idx = tid; idx < 288; idx += 256) wsh[idx] = w3[idx];

    const float* yn = y2 + (size_t)n * 32 * 2048;
    for (int idx = tid; idx < 32 * 320; idx += 256) {
        int r = idx / 320;
        int col = idx - r * 320;
        int q = reflect_idx(t0 - 32 + col, 4096);
        float src = fmaxf((float)q * 0.5f - 0.25f, 0.0f);
        int i0 = (int)src;
        float w = src - (float)i0;
        int i1 = i0 + 1 > 2047 ? 2047 : i0 + 1;
        const float* row = yn + r * 2048;
        float a = row[i0];
        float b = row[i1];
        us[r][col] = a + w * (b - a);
    }
    __syncthreads();

    float a0 = 0.0f, a1 = 0.0f, a2 = 0.0f;
#pragma unroll 8
    for (int ci = 0; ci < 32; ++ci) {
        float x0 = us[ci][tid];
        float x1 = us[ci][tid + 32];
        float x2 = us[ci][tid + 64];
        a0 = fmaf(wsh[(0 * 32 + ci) * 3 + 0], x0, a0);
        a0 = fmaf(wsh[(0 * 32 + ci) * 3 + 1], x1, a0);
        a0 = fmaf(wsh[(0 * 32 + ci) * 3 + 2], x2, a0);
        a1 = fmaf(wsh[(1 * 32 + ci) * 3 + 0], x0, a1);
        a1 = fmaf(wsh[(1 * 32 + ci) * 3 + 1], x1, a1);
        a1 = fmaf(wsh[(1 * 32 + ci) * 3 + 2], x2, a1);
        a2 = fmaf(wsh[(2 * 32 + ci) * 3 + 0], x0, a2);
        a2 = fmaf(wsh[(2 * 32 + ci) * 3 + 1], x1, a2);
        a2 = fmaf(wsh[(2 * 32 + ci) * 3 + 2], x2, a2);
    }
    int b = n >> 2, s = n & 3;
    int t = t0 + tid;
    size_t ob = ((size_t)(b * 3) * 4096 + t) * 4 + s;
    out[ob]         = a0 + bias[0];
    out[ob + 16384] = a1 + bias[1];
    out[ob + 32768] = a2 + bias[2];
}

// ---------------------------------------------------------------------------
__global__ void k4a_valid(const float* __restrict__ tg, float* lacc) {
    __shared__ int flag;
    if (threadIdx.x == 0) flag = 0;
    __syncthreads();
    int b = blockIdx.x >> 2, s = blockIdx.x & 3;
    bool any = false;
    for (int idx = threadIdx.x; idx < 3 * 4096; idx += 256) {
        int c = idx >> 12, t = idx & 4095;
        float v = tg[((size_t)(b * 3 + c) * 4096 + t) * 4 + s];
        any |= (v != 0.0f);
    }
    if (any) flag = 1;
    __syncthreads();
    if (threadIdx.x == 0 && flag) atomicAdd((int*)(lacc + 1), 1);
}

__global__ __launch_bounds__(256) void k4b_ce(
    const float* __restrict__ x, const float* __restrict__ tg, float* lacc)
{
    int i = blockIdx.x * 256 + threadIdx.x;
    int s = i & 3;
    int t = (i >> 2) & 4095;
    int b = i >> 14;
    size_t base = ((size_t)(b * 3) * 4096 + t) * 4 + s;
    float x0 = x[base], x1 = x[base + 16384], x2 = x[base + 32768];
    float mx = fmaxf(x0, fmaxf(x1, x2));
    float e0 = expf(x0 - mx), e1 = expf(x1 - mx), e2 = expf(x2 - mx);
    float lse = mx + logf(e0 + e1 + e2);
    float g0 = tg[base], g1 = tg[base + 16384], g2 = tg[base + 32768];
    float v = g0 * (lse - x0) + g1 * (lse - x1) + g2 * (lse - x2);

    for (int off = 32; off > 0; off >>= 1) v += __shfl_down(v, off);
    __shared__ float wsum[4];
    int lane = threadIdx.x & 63, wid = threadIdx.x >> 6;
    if (lane == 0) wsum[wid] = v;
    __syncthreads();
    if (threadIdx.x == 0) {
        atomicAdd(lacc, wsum[0] + wsum[1] + wsum[2] + wsum[3]);
    }
}

__global__ void k4c_final(const float* lacc, float* out) {
    if (threadIdx.x == 0) {
        float sum = lacc[0];
        int num = ((const int*)lacc)[1];
        out[786432] = sum / ((float)num * 4096.0f);
    }
}

// ---------------------------------------------------------------------------
extern "C" void kernel_launch(void* const* d_in, const int* in_sizes, int n_in,
                              void* d_out, int out_size, void* d_ws, size_t ws_size,
                              hipStream_t stream) {
    (void)in_sizes; (void)n_in; (void)out_size; (void)ws_size;
    const float* fusion  = (const float*)d_in[0];
    const float* targets = (const float*)d_in[1];
    const float* w1  = (const float*)d_in[2];
    const float* g1  = (const float*)d_in[3];
    const float* be1 = (const float*)d_in[4];
    const float* mn1 = (const float*)d_in[5];
    const float* vr1 = (const float*)d_in[6];
    const float* w2  = (const float*)d_in[7];
    const float* g2  = (const float*)d_in[8];
    const float* be2 = (const float*)d_in[9];
    const float* mn2 = (const float*)d_in[10];
    const float* vr2 = (const float*)d_in[11];
    const float* w3  = (const float*)d_in[12];
    const float* b3  = (const float*)d_in[13];
    float* out = (float*)d_out;

    char* ws = (char*)d_ws;
    unsigned short* y1 = (unsigned short*)ws;               // 33,554,432 B
    unsigned short* xb = (unsigned short*)(ws + 33554432);  // 16,777,216 B (aliases y2)
    float* y2   = (float*)(ws + 33554432);                  // same region, used after k1
    unsigned short* wb = (unsigned short*)(ws + 50331648);  //    786,432 B
    float* w2t  = (float*)(ws + 51118080);                  //     98,304 B
    float* lacc = (float*)(ws + 51216384);                  //        256 B

    k0_init<<<1, 64, 0, stream>>>(lacc);
    kw1b<<<1536, 256, 0, stream>>>(w1, wb);
    kt_w2<<<96, 256, 0, stream>>>(w2, w2t);
    for (int r = 0; r < 4; ++r) {
        kx_t<<<dim3(16, 8, 16), 256, 0, stream>>>(fusion, xb, r * 16);
        k1_mfma<<<dim3(16, 16), 256, 0, stream>>>(xb, wb, g1, be1, mn1, vr1, y1, r * 16);
    }
    k2_conv2<<<dim3(8, 64), 256, 0, stream>>>(y1, w2t, g2, be2, mn2, vr2, y2);
    k3_out<<<dim3(16, 64), 256, 0, stream>>>(y2, w3, b3, out);
    k4a_valid<<<64, 256, 0, stream>>>(targets, lacc);
    k4b_ce<<<1024, 256, 0, stream>>>(out, targets, lacc);
    k4c_final<<<1, 64, 0, stream>>>(lacc, out);
}

// Round 3
// 417.097 us; speedup vs baseline: 2.6307x; 1.4313x over previous
//
#include <hip/hip_runtime.h>
#include <hip/hip_bf16.h>

#define DEV static __device__ __forceinline__

typedef short bf16x8_t __attribute__((ext_vector_type(8)));
typedef float f32x4 __attribute__((ext_vector_type(4)));

#define GLDS16(gp, lp) __builtin_amdgcn_global_load_lds( \
    (const __attribute__((address_space(1))) void*)(gp), \
    (__attribute__((address_space(3))) void*)(lp), 16, 0, 0)

DEV int reflect_idx(int q, int L) {
    q = q < 0 ? -q : q;
    q = q >= L ? 2 * L - 2 - q : q;
    return q;
}

DEV unsigned short f2bf(float f) {
    unsigned int b = __float_as_uint(f);
    unsigned int r = (b + 0x7FFFu + ((b >> 16) & 1u)) >> 16;
    return (unsigned short)r;
}
DEV float bf2f(unsigned short u) {
    return __uint_as_float(((unsigned int)u) << 16);
}

// ---------------------------------------------------------------------------
__global__ void k0_init(float* lacc) {
    if (threadIdx.x < 8) lacc[threadIdx.x] = 0.0f;
}

// prep: w1 [256co][512ci][3kk] fp32 -> wb [3kk][256co][512ci] bf16
__global__ void kw1b(const float* __restrict__ w1, unsigned short* __restrict__ wb) {
    int idx = blockIdx.x * 256 + threadIdx.x;   // 393216
    int kk = idx >> 17;
    int rem = idx & 131071;
    int co = rem >> 9;
    int ci = rem & 511;
    wb[idx] = f2bf(w1[(co * 512 + ci) * 3 + kk]);
}

// prep: w2 [32co][256ci][3kk] fp32 -> w2b [3kk][32co][256ci] bf16
__global__ void kw2b(const float* __restrict__ w2, unsigned short* __restrict__ w2b) {
    int idx = blockIdx.x * 256 + threadIdx.x;   // 24576 = kk*8192 + co*256 + ci
    int ci = idx & 255;
    int co = (idx >> 8) & 31;
    int kk = idx >> 13;
    w2b[idx] = f2bf(w2[(co * 256 + ci) * 3 + kk]);
}

// prep: transpose x[n][512ci][1024t] fp32 -> xb[nr][1024t][512ci] bf16
__global__ __launch_bounds__(256) void kx_t(const float* __restrict__ x,
                                            unsigned short* __restrict__ xb, int n0) {
    __shared__ float ls[64][65];
    const int tid = threadIdx.x;
    const int t0 = blockIdx.x * 64, ci0 = blockIdx.y * 64;
    const int n = n0 + blockIdx.z;
    const float* xp = x + ((size_t)n * 512 + ci0) * 1024 + t0;
    for (int idx = tid; idx < 1024; idx += 256) {
        int r = idx >> 4, c4 = (idx & 15) * 4;
        float4 v = *(const float4*)(xp + r * 1024 + c4);
        ls[r][c4] = v.x; ls[r][c4 + 1] = v.y; ls[r][c4 + 2] = v.z; ls[r][c4 + 3] = v.w;
    }
    __syncthreads();
    unsigned short* xo = xb + ((size_t)blockIdx.z * 1024 + t0) * 512 + ci0;
#pragma unroll
    for (int p = 0; p < 2; ++p) {
        int trow = (tid >> 3) + p * 32;
        int cj = (tid & 7) * 8;
        unsigned short pk[8];
#pragma unroll
        for (int j = 0; j < 8; ++j) pk[j] = f2bf(ls[cj + j][trow]);
        *(uint4*)(xo + (size_t)trow * 512 + cj) = *(const uint4*)pk;
    }
}

// ---------------------------------------------------------------------------
// K1: conv1 (512->256, d=8, reflect) + bn1 + relu via bf16 MFMA 16x16x32.
// Output now TRANSPOSED: y1t[n][1024t][256co] bf16 (for k2's A-fragments).
__global__ __launch_bounds__(256, 1) void k1_mfma(
    const unsigned short* __restrict__ xb, const unsigned short* __restrict__ wb,
    const float* __restrict__ g, const float* __restrict__ be,
    const float* __restrict__ mn, const float* __restrict__ vr,
    unsigned short* __restrict__ y1t, int n0)
{
    const int tid  = threadIdx.x;
    const int lane = tid & 63;
    const int w    = tid >> 6;
    const int tq   = lane & 15;
    const int qd   = lane >> 4;
    const int t0   = blockIdx.x * 64;
    const int nr   = blockIdx.y;
    const int n    = n0 + nr;

    __shared__ unsigned short xs[2][80 * 32];      // staging (10 KB)
    __shared__ unsigned short us1[64 * 264];       // transpose epilogue (33.8 KB)

    const int r1 = tid >> 2;
    const int q1 = (tid & 3) ^ ((r1 >> 1) & 3);
    const unsigned short* gp0 =
        xb + ((size_t)nr * 1024 + reflect_idx(t0 - 8 + r1, 1024)) * 512 + q1 * 8;
    const unsigned short* gp1 =
        xb + ((size_t)nr * 1024 + reflect_idx(t0 - 8 + 64 + r1, 1024)) * 512 + q1 * 8;

    const int atom = qd ^ ((tq >> 1) & 3);
    const int xoff = tq * 32 + atom * 8;

    f32x4 acc[4][4];
#pragma unroll
    for (int a = 0; a < 4; ++a)
#pragma unroll
        for (int b = 0; b < 4; ++b) acc[a][b] = (f32x4){0.f, 0.f, 0.f, 0.f};

    const unsigned short* wlane = wb + ((size_t)(w * 64 + tq)) * 512 + qd * 8;

    GLDS16(gp0, &xs[0][tid * 8]);
    if (tid < 64) GLDS16(gp1, &xs[0][(256 + tid) * 8]);

    bf16x8_t Wf[4][3];
#pragma unroll
    for (int cs = 0; cs < 4; ++cs)
#pragma unroll
        for (int kk = 0; kk < 3; ++kk)
            Wf[cs][kk] = *(const bf16x8_t*)(wlane + (size_t)(kk * 256 + cs * 16) * 512);
    __syncthreads();

#pragma unroll
    for (int c = 0; c < 16; ++c) {
        const int pb = c & 1;
        if (c < 15) {
            GLDS16(gp0 + (c + 1) * 32, &xs[pb ^ 1][tid * 8]);
            if (tid < 64) GLDS16(gp1 + (c + 1) * 32, &xs[pb ^ 1][(256 + tid) * 8]);
        }
        bf16x8_t Wn[4][3];
        if (c < 15) {
#pragma unroll
            for (int cs = 0; cs < 4; ++cs)
#pragma unroll
                for (int kk = 0; kk < 3; ++kk)
                    Wn[cs][kk] = *(const bf16x8_t*)(wlane + (size_t)(kk * 256 + cs * 16) * 512 + (c + 1) * 32);
        }
#pragma unroll
        for (int ts = 0; ts < 4; ++ts) {
            bf16x8_t Xf[3];
#pragma unroll
            for (int kk = 0; kk < 3; ++kk)
                Xf[kk] = *(const bf16x8_t*)&xs[pb][xoff + (ts * 16 + kk * 8) * 32];
#pragma unroll
            for (int cs = 0; cs < 4; ++cs)
#pragma unroll
                for (int kk = 0; kk < 3; ++kk)
                    acc[ts][cs] = __builtin_amdgcn_mfma_f32_16x16x32_bf16(
                        Xf[kk], Wf[cs][kk], acc[ts][cs], 0, 0, 0);
        }
        __syncthreads();
        if (c < 15) {
#pragma unroll
            for (int cs = 0; cs < 4; ++cs)
#pragma unroll
                for (int kk = 0; kk < 3; ++kk)
                    Wf[cs][kk] = Wn[cs][kk];
        }
    }

    // epilogue: bn + relu -> bf16 -> LDS transpose [t][co] -> coalesced store
#pragma unroll
    for (int cs = 0; cs < 4; ++cs) {
        int co = w * 64 + cs * 16 + tq;
        float iv = g[co] / sqrtf(vr[co] + 1e-5f);
        float sh = be[co] - mn[co] * iv;
#pragma unroll
        for (int ts = 0; ts < 4; ++ts)
#pragma unroll
            for (int rg = 0; rg < 4; ++rg)
                us1[(ts * 16 + qd * 4 + rg) * 264 + co] =
                    f2bf(fmaxf(fmaf(acc[ts][cs][rg], iv, sh), 0.0f));
    }
    __syncthreads();
    const int row = tid >> 2, q = tid & 3;
    unsigned short* yp = y1t + ((size_t)n * 1024 + t0 + row) * 256 + q * 64;
#pragma unroll
    for (int j = 0; j < 8; ++j)
        *(uint4*)(yp + j * 8) = *(const uint4*)&us1[row * 264 + q * 64 + j * 8];
}

// ---------------------------------------------------------------------------
// K2: upsample2(y1t) -> conv2 (256->32, d=16) + bn2 + relu via bf16 MFMA.
// Block: 256 t_up x 32 co, 4 waves (wave = 64 t). K-chunks of 32 ci, 8 chunks.
// Tap offsets = 16 t = one tile shift: A-fragments Af[s=ts+kk], s in [0,6).
// Output TRANSPOSED fp32: y2t[n][2048t][32co].
__global__ __launch_bounds__(256, 2) void k2_mfma(
    const unsigned short* __restrict__ y1t, const unsigned short* __restrict__ w2b,
    const float* __restrict__ g, const float* __restrict__ be,
    const float* __restrict__ mn, const float* __restrict__ vr,
    float* __restrict__ y2t)
{
    const int tid  = threadIdx.x;
    const int lane = tid & 63;
    const int w    = tid >> 6;
    const int tq   = lane & 15;
    const int qd   = lane >> 4;
    const int t0   = blockIdx.x * 256;
    const int n    = blockIdx.y;

    __shared__ union SM {
        unsigned short us[288 * 40];   // staged upsampled rows, bf16, pad 40
        float tr[256 * 36];            // epilogue transpose, fp32, pad 36
    } sm;

    f32x4 acc[4][2];
#pragma unroll
    for (int a = 0; a < 4; ++a)
#pragma unroll
        for (int b = 0; b < 2; ++b) acc[a][b] = (f32x4){0.f, 0.f, 0.f, 0.f};

    const unsigned short* yn = y1t + (size_t)n * 1024 * 256;

    for (int ch = 0; ch < 8; ++ch) {
        const int ci0 = ch * 32;
        __syncthreads();
        // stage 288 rows x 32 ci (upsample lerp from y1t rows)
        for (int idx = tid; idx < 1152; idx += 256) {
            int r = idx >> 2, gq = idx & 3;
            int u = reflect_idx(t0 - 16 + r, 2048);
            float src = fmaxf((float)u * 0.5f - 0.25f, 0.0f);
            int i0 = (int)src;
            float wl = src - (float)i0;
            int i1 = i0 + 1 > 1023 ? 1023 : i0 + 1;
            const unsigned short* p0 = yn + (size_t)i0 * 256 + ci0 + gq * 8;
            const unsigned short* p1 = yn + (size_t)i1 * 256 + ci0 + gq * 8;
            uint4 ua = *(const uint4*)p0;
            uint4 ub = *(const uint4*)p1;
            const unsigned short* sa = (const unsigned short*)&ua;
            const unsigned short* sb = (const unsigned short*)&ub;
            unsigned short pk[8];
#pragma unroll
            for (int j = 0; j < 8; ++j) {
                float a = bf2f(sa[j]);
                float b = bf2f(sb[j]);
                pk[j] = f2bf(a + wl * (b - a));
            }
            *(uint4*)&sm.us[r * 40 + gq * 8] = *(const uint4*)pk;
        }
        __syncthreads();

        bf16x8_t Bf[2][3];
#pragma unroll
        for (int cs = 0; cs < 2; ++cs)
#pragma unroll
            for (int kk = 0; kk < 3; ++kk)
                Bf[cs][kk] = *(const bf16x8_t*)(w2b +
                    ((size_t)(kk * 32 + cs * 16 + tq)) * 256 + ci0 + qd * 8);

        bf16x8_t Af[6];
#pragma unroll
        for (int s = 0; s < 6; ++s)
            Af[s] = *(const bf16x8_t*)&sm.us[(w * 64 + s * 16 + tq) * 40 + qd * 8];

#pragma unroll
        for (int ts = 0; ts < 4; ++ts)
#pragma unroll
            for (int cs = 0; cs < 2; ++cs)
#pragma unroll
                for (int kk = 0; kk < 3; ++kk)
                    acc[ts][cs] = __builtin_amdgcn_mfma_f32_16x16x32_bf16(
                        Af[ts + kk], Bf[cs][kk], acc[ts][cs], 0, 0, 0);
    }

    __syncthreads();
    // epilogue: bn2 + relu -> fp32 LDS transpose [t][co] (pad 36)
#pragma unroll
    for (int cs = 0; cs < 2; ++cs) {
        int co = cs * 16 + tq;
        float iv = g[co] / sqrtf(vr[co] + 1e-5f);
        float sh = be[co] - mn[co] * iv;
#pragma unroll
        for (int ts = 0; ts < 4; ++ts)
#pragma unroll
            for (int rg = 0; rg < 4; ++rg) {
                int tl = w * 64 + ts * 16 + qd * 4 + rg;
                sm.tr[tl * 36 + co] = fmaxf(fmaf(acc[ts][cs][rg], iv, sh), 0.0f);
            }
    }
    __syncthreads();
    float* yo = y2t + ((size_t)n * 2048 + t0 + tid) * 32;
#pragma unroll
    for (int j = 0; j < 8; ++j)
        *(float4*)(yo + j * 4) = *(const float4*)&sm.tr[tid * 36 + j * 4];
}

// ---------------------------------------------------------------------------
// K3: upsample2(y2t) -> conv3 (32->3, d=32) + bias, transposed output store.
// Stages from y2t[t][ci] rows (coalesced) into us[ci][t] (pad 321, verified
// compute layout).
__global__ __launch_bounds__(256, 2) void k3_out(
    const float* __restrict__ y2t, const float* __restrict__ w3,
    const float* __restrict__ bias, float* __restrict__ out)
{
    const int tid = threadIdx.x;
    const int t0 = blockIdx.x * 256;
    const int n  = blockIdx.y;

    __shared__ float us[32 * 321];    // [ci][320 t rows], pad 321
    __shared__ float wsh[288];

    for (int idx = tid; idx < 288; idx += 256) wsh[idx] = w3[idx];

    const float* yn = y2t + (size_t)n * 2048 * 32;
    for (int idx = tid; idx < 1280; idx += 256) {
        int r = idx >> 2, gq = idx & 3;
        int u = reflect_idx(t0 - 32 + r, 4096);
        float src = fmaxf((float)u * 0.5f - 0.25f, 0.0f);
        int i0 = (int)src;
        float wl = src - (float)i0;
        int i1 = i0 + 1 > 2047 ? 2047 : i0 + 1;
        const float* p0 = yn + (size_t)i0 * 32 + gq * 8;
        const float* p1 = yn + (size_t)i1 * 32 + gq * 8;
        float4 a0 = *(const float4*)p0;
        float4 a1 = *(const float4*)(p0 + 4);
        float4 b0 = *(const float4*)p1;
        float4 b1 = *(const float4*)(p1 + 4);
        float v[8];
        v[0] = a0.x + wl * (b0.x - a0.x); v[1] = a0.y + wl * (b0.y - a0.y);
        v[2] = a0.z + wl * (b0.z - a0.z); v[3] = a0.w + wl * (b0.w - a0.w);
        v[4] = a1.x + wl * (b1.x - a1.x); v[5] = a1.y + wl * (b1.y - a1.y);
        v[6] = a1.z + wl * (b1.z - a1.z); v[7] = a1.w + wl * (b1.w - a1.w);
#pragma unroll
        for (int j = 0; j < 8; ++j)
            us[(gq * 8 + j) * 321 + r] = v[j];
    }
    __syncthreads();

    float a0 = 0.0f, a1 = 0.0f, a2 = 0.0f;
#pragma unroll 8
    for (int ci = 0; ci < 32; ++ci) {
        float x0 = us[ci * 321 + tid];
        float x1 = us[ci * 321 + tid + 32];
        float x2 = us[ci * 321 + tid + 64];
        a0 = fmaf(wsh[(0 * 32 + ci) * 3 + 0], x0, a0);
        a0 = fmaf(wsh[(0 * 32 + ci) * 3 + 1], x1, a0);
        a0 = fmaf(wsh[(0 * 32 + ci) * 3 + 2], x2, a0);
        a1 = fmaf(wsh[(1 * 32 + ci) * 3 + 0], x0, a1);
        a1 = fmaf(wsh[(1 * 32 + ci) * 3 + 1], x1, a1);
        a1 = fmaf(wsh[(1 * 32 + ci) * 3 + 2], x2, a1);
        a2 = fmaf(wsh[(2 * 32 + ci) * 3 + 0], x0, a2);
        a2 = fmaf(wsh[(2 * 32 + ci) * 3 + 1], x1, a2);
        a2 = fmaf(wsh[(2 * 32 + ci) * 3 + 2], x2, a2);
    }
    int b = n >> 2, s = n & 3;
    int t = t0 + tid;
    size_t ob = ((size_t)(b * 3) * 4096 + t) * 4 + s;
    out[ob]         = a0 + bias[0];
    out[ob + 16384] = a1 + bias[1];
    out[ob + 32768] = a2 + bias[2];
}

// ---------------------------------------------------------------------------
__global__ void k4a_valid(const float* __restrict__ tg, float* lacc) {
    __shared__ int flag;
    if (threadIdx.x == 0) flag = 0;
    __syncthreads();
    int b = blockIdx.x >> 2, s = blockIdx.x & 3;
    bool any = false;
    for (int idx = threadIdx.x; idx < 3 * 4096; idx += 256) {
        int c = idx >> 12, t = idx & 4095;
        float v = tg[((size_t)(b * 3 + c) * 4096 + t) * 4 + s];
        any |= (v != 0.0f);
    }
    if (any) flag = 1;
    __syncthreads();
    if (threadIdx.x == 0 && flag) atomicAdd((int*)(lacc + 1), 1);
}

__global__ __launch_bounds__(256) void k4b_ce(
    const float* __restrict__ x, const float* __restrict__ tg, float* lacc)
{
    int i = blockIdx.x * 256 + threadIdx.x;
    int s = i & 3;
    int t = (i >> 2) & 4095;
    int b = i >> 14;
    size_t base = ((size_t)(b * 3) * 4096 + t) * 4 + s;
    float x0 = x[base], x1 = x[base + 16384], x2 = x[base + 32768];
    float mx = fmaxf(x0, fmaxf(x1, x2));
    float e0 = expf(x0 - mx), e1 = expf(x1 - mx), e2 = expf(x2 - mx);
    float lse = mx + logf(e0 + e1 + e2);
    float g0 = tg[base], g1 = tg[base + 16384], g2 = tg[base + 32768];
    float v = g0 * (lse - x0) + g1 * (lse - x1) + g2 * (lse - x2);

    for (int off = 32; off > 0; off >>= 1) v += __shfl_down(v, off);
    __shared__ float wsum[4];
    int lane = threadIdx.x & 63, wid = threadIdx.x >> 6;
    if (lane == 0) wsum[wid] = v;
    __syncthreads();
    if (threadIdx.x == 0) {
        atomicAdd(lacc, wsum[0] + wsum[1] + wsum[2] + wsum[3]);
    }
}

__global__ void k4c_final(const float* lacc, float* out) {
    if (threadIdx.x == 0) {
        float sum = lacc[0];
        int num = ((const int*)lacc)[1];
        out[786432] = sum / ((float)num * 4096.0f);
    }
}

// ---------------------------------------------------------------------------
extern "C" void kernel_launch(void* const* d_in, const int* in_sizes, int n_in,
                              void* d_out, int out_size, void* d_ws, size_t ws_size,
                              hipStream_t stream) {
    (void)in_sizes; (void)n_in; (void)out_size;
    const float* fusion  = (const float*)d_in[0];
    const float* targets = (const float*)d_in[1];
    const float* w1  = (const float*)d_in[2];
    const float* g1  = (const float*)d_in[3];
    const float* be1 = (const float*)d_in[4];
    const float* mn1 = (const float*)d_in[5];
    const float* vr1 = (const float*)d_in[6];
    const float* w2  = (const float*)d_in[7];
    const float* g2  = (const float*)d_in[8];
    const float* be2 = (const float*)d_in[9];
    const float* mn2 = (const float*)d_in[10];
    const float* vr2 = (const float*)d_in[11];
    const float* w3  = (const float*)d_in[12];
    const float* b3  = (const float*)d_in[13];
    float* out = (float*)d_out;

    char* ws = (char*)d_ws;
    unsigned short* y1t = (unsigned short*)ws;              // 33,554,432 B
    unsigned short* xb  = (unsigned short*)(ws + 33554432); // 16 or 64 MB
    float* y2t = (float*)(ws + 33554432);                   // 16 MB, aliases xb

    const bool single = ws_size >= 101500000ull;
    size_t woff = single ? (33554432ull + 67108864ull) : (33554432ull + 16777216ull);
    unsigned short* wb  = (unsigned short*)(ws + woff);            // 786,432 B
    unsigned short* w2b = (unsigned short*)(ws + woff + 786432);   //  49,152 B
    float* lacc = (float*)(ws + woff + 786432 + 49152);            //     256 B

    k0_init<<<1, 64, 0, stream>>>(lacc);
    kw1b<<<1536, 256, 0, stream>>>(w1, wb);
    kw2b<<<96, 256, 0, stream>>>(w2, w2b);
    if (single) {
        kx_t<<<dim3(16, 8, 64), 256, 0, stream>>>(fusion, xb, 0);
        k1_mfma<<<dim3(16, 64), 256, 0, stream>>>(xb, wb, g1, be1, mn1, vr1, y1t, 0);
    } else {
        for (int r = 0; r < 4; ++r) {
            kx_t<<<dim3(16, 8, 16), 256, 0, stream>>>(fusion, xb, r * 16);
            k1_mfma<<<dim3(16, 16), 256, 0, stream>>>(xb, wb, g1, be1, mn1, vr1, y1t, r * 16);
        }
    }
    k2_mfma<<<dim3(8, 64), 256, 0, stream>>>(y1t, w2b, g2, be2, mn2, vr2, y2t);
    k3_out<<<dim3(16, 64), 256, 0, stream>>>(y2t, w3, b3, out);
    k4a_valid<<<64, 256, 0, stream>>>(targets, lacc);
    k4b_ce<<<1024, 256, 0, stream>>>(out, targets, lacc);
    k4c_final<<<1, 64, 0, stream>>>(lacc, out);
}